// Round 2
// baseline (1872.086 us; speedup 1.0000x reference)
//
#include <hip/hip_runtime.h>
#include <stdint.h>
#include <stddef.h>

#define MSTEPS 128
#define NB 1024
#define ED 512
#define GD 1536
#define VS 32000

typedef __attribute__((ext_vector_type(4))) float f32x4;
typedef __attribute__((ext_vector_type(8))) short s16x8;
typedef __attribute__((ext_vector_type(4))) short s16x4;
typedef __attribute__((ext_vector_type(8))) unsigned short u16x8;

__device__ __forceinline__ unsigned short f2bf(float f) {
  unsigned x = __builtin_bit_cast(unsigned, f);
  x = x + 0x7fffu + ((x >> 16) & 1u);
  return (unsigned short)(x >> 16);
}
__device__ __forceinline__ float bf2f(unsigned short u) {
  return __builtin_bit_cast(float, ((unsigned)u) << 16);
}
__device__ __forceinline__ float sigm(float x) { return 1.0f / (1.0f + __expf(-x)); }
__device__ __forceinline__ float tanh_(float x) {
  x = fminf(15.0f, fmaxf(-15.0f, x));
  float e = __expf(-2.0f * x);
  return (1.0f - e) / (1.0f + e);
}

// ---------------- Kernel 1: projected vocab table ----------------
// tab[v][g] = sum_k bf16(emb[v,k]) * bf16(Wih[g,k]) + bih[g], stored bf16.
// 128x128 tile, 4 waves (2x2 of 64x64), 16x16x32 bf16 MFMA, K staged in BK=64.
__global__ __launch_bounds__(256) void table_kernel(
    const float* __restrict__ emb, const float* __restrict__ Wih,
    const float* __restrict__ bih, unsigned short* __restrict__ tab)
{
  __shared__ short Al[128 * 64];
  __shared__ short Bl[128 * 64];
  const int tid = threadIdx.x;
  const int lane = tid & 63;
  const int l15 = lane & 15, l4 = lane >> 4;
  const int wv = tid >> 6;
  const int rh = wv & 1, ch = wv >> 1;
  const int row0 = blockIdx.x * 128;
  const int col0 = blockIdx.y * 128;

  f32x4 acc[4][4];
  #pragma unroll
  for (int m = 0; m < 4; m++)
    #pragma unroll
    for (int n = 0; n < 4; n++) acc[m][n] = (f32x4){0.f, 0.f, 0.f, 0.f};

  for (int ko = 0; ko < ED; ko += 64) {
    #pragma unroll
    for (int i = 0; i < 8; i++) {
      int idx = tid + i * 256;        // 0..2047 = 128 rows x 16 float4
      int r = idx >> 4, c4 = idx & 15;
      int ba = (r * 128 + c4 * 8) ^ ((r & 7) << 4);
      f32x4 va = *(const f32x4*)(emb + (size_t)(row0 + r) * ED + ko + c4 * 4);
      s16x4 pa;
      pa[0] = (short)f2bf(va[0]); pa[1] = (short)f2bf(va[1]);
      pa[2] = (short)f2bf(va[2]); pa[3] = (short)f2bf(va[3]);
      *(s16x4*)((char*)Al + ba) = pa;
      f32x4 vb = *(const f32x4*)(Wih + (size_t)(col0 + r) * ED + ko + c4 * 4);
      s16x4 pb;
      pb[0] = (short)f2bf(vb[0]); pb[1] = (short)f2bf(vb[1]);
      pb[2] = (short)f2bf(vb[2]); pb[3] = (short)f2bf(vb[3]);
      *(s16x4*)((char*)Bl + ba) = pb;
    }
    __syncthreads();
    #pragma unroll
    for (int kk = 0; kk < 2; kk++) {
      s16x8 af[4], bfv[4];
      #pragma unroll
      for (int m = 0; m < 4; m++) {
        int row = rh * 64 + m * 16 + l15;
        int ad = (row * 128 + kk * 64 + l4 * 16) ^ ((row & 7) << 4);
        af[m] = *(const s16x8*)((char*)Al + ad);
      }
      #pragma unroll
      for (int n = 0; n < 4; n++) {
        int col = ch * 64 + n * 16 + l15;
        int ad = (col * 128 + kk * 64 + l4 * 16) ^ ((col & 7) << 4);
        bfv[n] = *(const s16x8*)((char*)Bl + ad);
      }
      #pragma unroll
      for (int m = 0; m < 4; m++)
        #pragma unroll
        for (int n = 0; n < 4; n++)
          acc[m][n] = __builtin_amdgcn_mfma_f32_16x16x32_bf16(af[m], bfv[n], acc[m][n], 0, 0, 0);
    }
    __syncthreads();
  }

  float bias_n[4];
  #pragma unroll
  for (int n = 0; n < 4; n++) bias_n[n] = bih[col0 + ch * 64 + n * 16 + l15];
  #pragma unroll
  for (int m = 0; m < 4; m++)
    #pragma unroll
    for (int n = 0; n < 4; n++) {
      int colg = col0 + ch * 64 + n * 16 + l15;
      #pragma unroll
      for (int j = 0; j < 4; j++) {
        int rowg = row0 + rh * 64 + m * 16 + l4 * 4 + j;
        tab[(size_t)rowg * GD + colg] = f2bf(acc[m][n][j] + bias_n[n]);
      }
    }
}

// ---------------- Kernel 2: persistent GRU scan ----------------
// Grid 256 = 16 row-blocks (64 rows) x 16 col-blocks (32 state cols).
// W_hh slice (96 gate-rows x 512) LDS-resident bf16, XOR-swizzled.
// State exchanged via agent-scope atomics (coherent across XCDs);
// f32 master state lives in registers. Per-row-block barrier each step.
#define LDS_W 0
#define LDS_GI 98304
#define LDS_ST (98304 + 12288)
#define LDS_FLAG (98304 + 12288 + 4096)
#define LDS_TOTAL 114944

__global__ __launch_bounds__(256, 1) void gru_kernel(
    const int* __restrict__ utt, const float* __restrict__ Whh,
    const float* __restrict__ bhh, const unsigned short* __restrict__ tab,
    unsigned short* st0, unsigned short* st1,
    unsigned* cnt, int* abort_g, const int* __restrict__ termp,
    float* __restrict__ out)
{
  extern __shared__ char smem[];
  unsigned short* gil = (unsigned short*)(smem + LDS_GI); // [64][96]
  unsigned short* stl = (unsigned short*)(smem + LDS_ST); // [64][32]
  volatile int* abl = (volatile int*)(smem + LDS_FLAG);

  const int tid = threadIdx.x;
  const int lane = tid & 63;
  const int l15 = lane & 15, l4 = lane >> 4;
  const int wv = tid >> 6;
  const int rh = wv & 1;      // row half (32 rows)
  const int hh = wv >> 1;     // col half (16 state cols)
  const int bid = blockIdx.x;
  const int rblk = bid & 15, cblk = bid >> 4;
  const int r0 = rblk * 64, c0 = cblk * 32;
  const int termid = termp[0];
  unsigned* cnt_r = cnt + rblk * 32;

  // ---- stage W_hh slice -> LDS bf16 swizzled (one time) ----
  for (int i = tid; i < 96 * 64; i += 256) {
    int g = i >> 6, blk = i & 63;
    int mg = (g >> 5) * ED + c0 + (g & 31);   // global W_hh row (gate*512 + col)
    const float* src = Whh + (size_t)mg * ED + blk * 8;
    f32x4 v0 = *(const f32x4*)(src);
    f32x4 v1 = *(const f32x4*)(src + 4);
    s16x8 p;
    p[0] = (short)f2bf(v0[0]); p[1] = (short)f2bf(v0[1]);
    p[2] = (short)f2bf(v0[2]); p[3] = (short)f2bf(v0[3]);
    p[4] = (short)f2bf(v1[0]); p[5] = (short)f2bf(v1[1]);
    p[6] = (short)f2bf(v1[2]); p[7] = (short)f2bf(v1[3]);
    int ad = ((g << 10) + blk * 16) ^ ((g & 7) << 4);
    *(s16x8*)(smem + LDS_W + ad) = p;
  }

  const int scl = hh * 16 + l15;              // local state col 0..31
  float bh[3];
  #pragma unroll
  for (int g = 0; g < 3; g++) bh[g] = bhh[g * ED + c0 + scl];

  int grow[3];
  #pragma unroll
  for (int g = 0; g < 3; g++) grow[g] = g * 32 + hh * 16 + l15; // LDS W row

  float ms[2][4] = {{0.f, 0.f, 0.f, 0.f}, {0.f, 0.f, 0.f, 0.f}};
  unsigned am = 0xFFu;                        // alive bits for 8 owned rows
  const int gt = tid >> 2, q = tid & 3;       // gather: row 0..63, quarter

  __syncthreads();

  for (int s = 0; s < MSTEPS; s++) {
    const unsigned short* rdb = (s & 1) ? st1 : st0;
    unsigned short* wrb = (s & 1) ? st0 : st1;

    // tokens for alive update (8 rows/lane)
    int toks[2][4];
    #pragma unroll
    for (int a = 0; a < 2; a++)
      #pragma unroll
      for (int j = 0; j < 4; j++)
        toks[a][j] = utt[s * NB + r0 + rh * 32 + a * 16 + l4 * 4 + j];

    // A prefetch: state rows, coherent (bypass stale L1/L2)
    unsigned long long ap[2][16][2];
    #pragma unroll
    for (int a = 0; a < 2; a++) {
      int n = r0 + rh * 32 + a * 16 + l15;
      const unsigned long long* base =
          (const unsigned long long*)(rdb + (size_t)n * ED);
      #pragma unroll
      for (int kk = 0; kk < 16; kk++) {
        int ki = (kk * 32 + l4 * 8) >> 2;   // ull index
        ap[a][kk][0] = __hip_atomic_load(base + ki, __ATOMIC_RELAXED, __HIP_MEMORY_SCOPE_AGENT);
        ap[a][kk][1] = __hip_atomic_load(base + ki + 1, __ATOMIC_RELAXED, __HIP_MEMORY_SCOPE_AGENT);
      }
    }

    // gi gather from projected table (plain loads; read-only data)
    int tok = utt[s * NB + r0 + gt];
    const unsigned short* tb = tab + (size_t)tok * GD + c0 + q * 8;
    u16x8 gv0 = *(const u16x8*)(tb);
    u16x8 gv1 = *(const u16x8*)(tb + ED);
    u16x8 gv2 = *(const u16x8*)(tb + 2 * ED);

    // GEMM: gh = state @ Whh^T  (2 row-frags x 3 gates)
    f32x4 acc[2][3];
    #pragma unroll
    for (int a = 0; a < 2; a++)
      #pragma unroll
      for (int g = 0; g < 3; g++) acc[a][g] = (f32x4){0.f, 0.f, 0.f, 0.f};
    #pragma unroll
    for (int kk = 0; kk < 16; kk++) {
      s16x8 bfr[3];
      #pragma unroll
      for (int g = 0; g < 3; g++) {
        int ad = (grow[g] * 1024 + kk * 64 + l4 * 16) ^ ((grow[g] & 7) << 4);
        bfr[g] = *(const s16x8*)(smem + LDS_W + ad);
      }
      #pragma unroll
      for (int a = 0; a < 2; a++) {
        union { unsigned long long u[2]; s16x8 s8; } cv;
        cv.u[0] = ap[a][kk][0]; cv.u[1] = ap[a][kk][1];
        #pragma unroll
        for (int g = 0; g < 3; g++)
          acc[a][g] = __builtin_amdgcn_mfma_f32_16x16x32_bf16(cv.s8, bfr[g], acc[a][g], 0, 0, 0);
      }
    }

    // park gi in LDS
    {
      char* gb = (char*)gil + gt * 192;
      *(u16x8*)(gb + 0 * 64 + q * 16) = gv0;
      *(u16x8*)(gb + 1 * 64 + q * 16) = gv1;
      *(u16x8*)(gb + 2 * 64 + q * 16) = gv2;
    }
    __syncthreads();

    // epilogue: gates + blend (lane-local; master state in f32 regs)
    #pragma unroll
    for (int a = 0; a < 2; a++) {
      #pragma unroll
      for (int j = 0; j < 4; j++) {
        int rloc = rh * 32 + a * 16 + l4 * 4 + j;
        float hr = acc[a][0][j] + bh[0];
        float hz = acc[a][1][j] + bh[1];
        float hn = acc[a][2][j] + bh[2];
        float ir = bf2f(gil[rloc * 96 + 0 * 32 + scl]);
        float iz = bf2f(gil[rloc * 96 + 1 * 32 + scl]);
        float in_ = bf2f(gil[rloc * 96 + 2 * 32 + scl]);
        float r = sigm(ir + hr);
        float z = sigm(iz + hz);
        float nn = tanh_(in_ + r * hn);
        float old = ms[a][j];
        float nu = (1.0f - z) * nn + z * old;
        float res = ((am >> (a * 4 + j)) & 1u) ? nu : old;
        ms[a][j] = res;
        stl[rloc * 32 + scl] = f2bf(res);
        if (toks[a][j] == termid) am &= ~(1u << (a * 4 + j));
      }
    }
    __syncthreads();

    // cooperative coherent store of new state tile
    {
      union { s16x8 s8; unsigned long long u[2]; } cv;
      cv.s8 = *(s16x8*)((char*)stl + gt * 64 + q * 16);
      unsigned long long* dst =
          (unsigned long long*)(wrb + (size_t)(r0 + gt) * ED + c0 + q * 8);
      __hip_atomic_store(dst, cv.u[0], __ATOMIC_RELAXED, __HIP_MEMORY_SCOPE_AGENT);
      __hip_atomic_store(dst + 1, cv.u[1], __ATOMIC_RELAXED, __HIP_MEMORY_SCOPE_AGENT);
    }

    // per-row-block barrier (16 WGs), with timeout -> abort (no hang)
    asm volatile("s_waitcnt vmcnt(0)" ::: "memory");
    __syncthreads();
    if (tid == 0) {
      __hip_atomic_fetch_add(cnt_r, 1u, __ATOMIC_RELEASE, __HIP_MEMORY_SCOPE_AGENT);
      unsigned target = 16u * (unsigned)(s + 1);
      unsigned long long t0 = __builtin_amdgcn_s_memrealtime();
      int ab = 0, pc = 0;
      while (__hip_atomic_load(cnt_r, __ATOMIC_RELAXED, __HIP_MEMORY_SCOPE_AGENT) < target) {
        if (((++pc) & 63) == 0) {
          if (__hip_atomic_load(abort_g, __ATOMIC_RELAXED, __HIP_MEMORY_SCOPE_AGENT)) { ab = 1; break; }
          if (__builtin_amdgcn_s_memrealtime() - t0 > 20000000ULL) {
            __hip_atomic_store(abort_g, 1, __ATOMIC_RELAXED, __HIP_MEMORY_SCOPE_AGENT);
            ab = 1; break;
          }
        }
      }
      *abl = ab;
    }
    __syncthreads();
    if (*abl) break;
  }

  // final f32 state -> d_out
  #pragma unroll
  for (int a = 0; a < 2; a++)
    #pragma unroll
    for (int j = 0; j < 4; j++) {
      int n = r0 + rh * 32 + a * 16 + l4 * 4 + j;
      out[(size_t)n * ED + c0 + scl] = ms[a][j];
    }
}

__global__ void fail_kernel(float* out) {
  if (threadIdx.x == 0 && blockIdx.x == 0) out[0] = -54321.0f;
}

extern "C" void kernel_launch(void* const* d_in, const int* in_sizes, int n_in,
                              void* d_out, int out_size, void* d_ws, size_t ws_size,
                              hipStream_t stream) {
  const int* utt = (const int*)d_in[0];
  const float* emb = (const float*)d_in[1];
  const float* Wih = (const float*)d_in[2];
  const float* Whh = (const float*)d_in[3];
  const float* bih = (const float*)d_in[4];
  const float* bhh = (const float*)d_in[5];
  const int* term = (const int*)d_in[6];
  float* out = (float*)d_out;
  char* ws = (char*)d_ws;

  const size_t tab_b = (size_t)VS * GD * 2;                 // 98,304,000
  const size_t st_b = (size_t)NB * ED * 2;                  // 1,048,576
  const size_t off_st0 = tab_b;
  const size_t off_st1 = off_st0 + st_b;
  const size_t off_cnt = off_st1 + st_b;
  const size_t need = off_cnt + 4096;

  if (ws_size < need) {  // sentinel: visible failure instead of OOB
    fail_kernel<<<1, 64, 0, stream>>>(out);
    return;
  }

  unsigned short* tab = (unsigned short*)(ws);
  unsigned short* st0 = (unsigned short*)(ws + off_st0);
  unsigned short* st1 = (unsigned short*)(ws + off_st1);
  unsigned* cnt = (unsigned*)(ws + off_cnt);
  int* abort_g = (int*)(ws + off_cnt + 2048);

  (void)hipFuncSetAttribute((const void*)gru_kernel,
                            hipFuncAttributeMaxDynamicSharedMemorySize, LDS_TOTAL);

  (void)hipMemsetAsync(st0, 0, st_b, stream);
  (void)hipMemsetAsync(cnt, 0, 4096, stream);

  table_kernel<<<dim3(250, 12), 256, 0, stream>>>(emb, Wih, bih, tab);
  gru_kernel<<<256, 256, LDS_TOTAL, stream>>>(utt, Whh, bhh, tab, st0, st1,
                                              cnt, abort_g, term, out);
}

// Round 3
// 942.144 us; speedup vs baseline: 1.9870x; 1.9870x over previous
//
#include <hip/hip_runtime.h>
#include <stdint.h>
#include <stddef.h>

#define MSTEPS 128
#define NB 1024
#define ED 512
#define GD 1536
#define VS 32000

// GRU decomposition: 32 row-blocks x 32 rows, 8 col-WGs x 64 cols.
#define RB 32    // rows per row-block
#define CB 64    // cols per WG
#define NRB 32
#define NCB 8
#define GIST 200 // gi LDS row stride (elems)
#define STST 80  // stl LDS row stride (elems)

typedef __attribute__((ext_vector_type(4))) float f32x4;
typedef __attribute__((ext_vector_type(8))) short s16x8;
typedef __attribute__((ext_vector_type(4))) short s16x4;
typedef __attribute__((ext_vector_type(8))) unsigned short u16x8;

__device__ __forceinline__ unsigned short f2bf(float f) {
  unsigned x = __builtin_bit_cast(unsigned, f);
  x = x + 0x7fffu + ((x >> 16) & 1u);
  return (unsigned short)(x >> 16);
}
__device__ __forceinline__ float bf2f(unsigned short u) {
  return __builtin_bit_cast(float, ((unsigned)u) << 16);
}
__device__ __forceinline__ float sigm(float x) { return 1.0f / (1.0f + __expf(-x)); }
__device__ __forceinline__ float tanh_(float x) {
  x = fminf(15.0f, fmaxf(-15.0f, x));
  float e = __expf(-2.0f * x);
  return (1.0f - e) / (1.0f + e);
}

// ---------------- Kernel 1: projected vocab table (unchanged) ----------------
__global__ __launch_bounds__(256) void table_kernel(
    const float* __restrict__ emb, const float* __restrict__ Wih,
    const float* __restrict__ bih, unsigned short* __restrict__ tab)
{
  __shared__ short Al[128 * 64];
  __shared__ short Bl[128 * 64];
  const int tid = threadIdx.x;
  const int lane = tid & 63;
  const int l15 = lane & 15, l4 = lane >> 4;
  const int wv = tid >> 6;
  const int rh = wv & 1, ch = wv >> 1;
  const int row0 = blockIdx.x * 128;
  const int col0 = blockIdx.y * 128;

  f32x4 acc[4][4];
  #pragma unroll
  for (int m = 0; m < 4; m++)
    #pragma unroll
    for (int n = 0; n < 4; n++) acc[m][n] = (f32x4){0.f, 0.f, 0.f, 0.f};

  for (int ko = 0; ko < ED; ko += 64) {
    #pragma unroll
    for (int i = 0; i < 8; i++) {
      int idx = tid + i * 256;
      int r = idx >> 4, c4 = idx & 15;
      int ba = (r * 128 + c4 * 8) ^ ((r & 7) << 4);
      f32x4 va = *(const f32x4*)(emb + (size_t)(row0 + r) * ED + ko + c4 * 4);
      s16x4 pa;
      pa[0] = (short)f2bf(va[0]); pa[1] = (short)f2bf(va[1]);
      pa[2] = (short)f2bf(va[2]); pa[3] = (short)f2bf(va[3]);
      *(s16x4*)((char*)Al + ba) = pa;
      f32x4 vb = *(const f32x4*)(Wih + (size_t)(col0 + r) * ED + ko + c4 * 4);
      s16x4 pb;
      pb[0] = (short)f2bf(vb[0]); pb[1] = (short)f2bf(vb[1]);
      pb[2] = (short)f2bf(vb[2]); pb[3] = (short)f2bf(vb[3]);
      *(s16x4*)((char*)Bl + ba) = pb;
    }
    __syncthreads();
    #pragma unroll
    for (int kk = 0; kk < 2; kk++) {
      s16x8 af[4], bfv[4];
      #pragma unroll
      for (int m = 0; m < 4; m++) {
        int row = rh * 64 + m * 16 + l15;
        int ad = (row * 128 + kk * 64 + l4 * 16) ^ ((row & 7) << 4);
        af[m] = *(const s16x8*)((char*)Al + ad);
      }
      #pragma unroll
      for (int n = 0; n < 4; n++) {
        int col = ch * 64 + n * 16 + l15;
        int ad = (col * 128 + kk * 64 + l4 * 16) ^ ((col & 7) << 4);
        bfv[n] = *(const s16x8*)((char*)Bl + ad);
      }
      #pragma unroll
      for (int m = 0; m < 4; m++)
        #pragma unroll
        for (int n = 0; n < 4; n++)
          acc[m][n] = __builtin_amdgcn_mfma_f32_16x16x32_bf16(af[m], bfv[n], acc[m][n], 0, 0, 0);
    }
    __syncthreads();
  }

  float bias_n[4];
  #pragma unroll
  for (int n = 0; n < 4; n++) bias_n[n] = bih[col0 + ch * 64 + n * 16 + l15];
  #pragma unroll
  for (int m = 0; m < 4; m++)
    #pragma unroll
    for (int n = 0; n < 4; n++) {
      int colg = col0 + ch * 64 + n * 16 + l15;
      #pragma unroll
      for (int j = 0; j < 4; j++) {
        int rowg = row0 + rh * 64 + m * 16 + l4 * 4 + j;
        tab[(size_t)rowg * GD + colg] = f2bf(acc[m][n][j] + bias_n[n]);
      }
    }
}

// ---------------- Kernel 2: persistent GRU scan ----------------
// 256 WGs = 32 row-blocks x 8 col-WGs. W_hh fragment lives in VGPRs
// (192/lane). State tile [32][512] bf16 staged in LDS each step via
// coalesced agent-scope loads. gi gather prefetched one step ahead.
__global__ __launch_bounds__(256, 1) void gru_kernel(
    const int* __restrict__ utt, const float* __restrict__ Whh,
    const float* __restrict__ bhh, const unsigned short* __restrict__ tab,
    unsigned short* st0, unsigned short* st1,
    unsigned* cnt, int* abort_g, const int* __restrict__ termp,
    float* __restrict__ out)
{
  __shared__ __align__(16) char sls[RB * 1024];            // state tile 32KB
  __shared__ __align__(16) unsigned short gil[RB * GIST];  // 12.5KB
  __shared__ __align__(16) unsigned short stl[RB * STST];  // 5KB
  __shared__ int abl;

  const int tid = threadIdx.x;
  const int lane = tid & 63;
  const int l15 = lane & 15, l4 = lane >> 4;
  const int wv = tid >> 6;
  const int bid = blockIdx.x;
  const int rblk = bid & (NRB - 1), cblk = bid >> 5;
  const int r0 = rblk * RB, c0 = cblk * CB;
  const int wc = wv * 16 + l15;          // col within WG tile, 0..63
  const int termid = termp[0];
  unsigned* cnt_r = cnt + rblk * 32;
  const int grow = tid >> 3, gq = tid & 7;   // gather: row 0..31, eighth

  // ---- W_hh fragments -> VGPRs (held for all 128 steps) ----
  s16x8 bfr[3][16];
  #pragma unroll
  for (int g = 0; g < 3; g++)
    #pragma unroll
    for (int kk = 0; kk < 16; kk++) {
      const float* src = Whh + (size_t)(g * ED + c0 + wc) * ED + kk * 32 + l4 * 8;
      f32x4 v0 = *(const f32x4*)(src);
      f32x4 v1 = *(const f32x4*)(src + 4);
      s16x8 p;
      p[0] = (short)f2bf(v0[0]); p[1] = (short)f2bf(v0[1]);
      p[2] = (short)f2bf(v0[2]); p[3] = (short)f2bf(v0[3]);
      p[4] = (short)f2bf(v1[0]); p[5] = (short)f2bf(v1[1]);
      p[6] = (short)f2bf(v1[2]); p[7] = (short)f2bf(v1[3]);
      bfr[g][kk] = p;
    }

  float bh[3];
  #pragma unroll
  for (int g = 0; g < 3; g++) bh[g] = bhh[g * ED + c0 + wc];

  float ms[2][4] = {{0.f, 0.f, 0.f, 0.f}, {0.f, 0.f, 0.f, 0.f}};
  unsigned am = 0xFFu;

  // gi/token prefetch registers (step s+1 loaded during step s)
  u16x8 pg0, pg1, pg2;
  int ptoks[8];
  {
    int tok = utt[r0 + grow];
    const unsigned short* tb = tab + (size_t)tok * GD + c0 + gq * 8;
    pg0 = *(const u16x8*)(tb);
    pg1 = *(const u16x8*)(tb + ED);
    pg2 = *(const u16x8*)(tb + 2 * ED);
    #pragma unroll
    for (int a = 0; a < 2; a++)
      #pragma unroll
      for (int j = 0; j < 4; j++)
        ptoks[a * 4 + j] = utt[r0 + a * 16 + l4 * 4 + j];
  }

  for (int s = 0; s < MSTEPS; s++) {
    const unsigned short* rdb = (s & 1) ? st1 : st0;
    unsigned short* wrb = (s & 1) ? st0 : st1;

    // 1) coalesced agent-scope state load (32KB/WG, 16 x 8B per thread)
    unsigned long long sld[16];
    const unsigned long long* sb = (const unsigned long long*)(rdb + (size_t)r0 * ED);
    #pragma unroll
    for (int i = 0; i < 16; i++)
      sld[i] = __hip_atomic_load(sb + i * 256 + tid, __ATOMIC_RELAXED, __HIP_MEMORY_SCOPE_AGENT);

    // 2) park prefetched gi into LDS; snapshot tokens
    {
      char* gb = (char*)gil + grow * (GIST * 2) + gq * 16;
      *(u16x8*)(gb + 0 * 128) = pg0;
      *(u16x8*)(gb + 1 * 128) = pg1;
      *(u16x8*)(gb + 2 * 128) = pg2;
    }
    int tk[8];
    #pragma unroll
    for (int i = 0; i < 8; i++) tk[i] = ptoks[i];

    // 3) state -> LDS, XOR-swizzled rows
    #pragma unroll
    for (int i = 0; i < 16; i++) {
      int o = i * 2048 + tid * 8;
      int row = o >> 10;
      *(unsigned long long*)(sls + (o ^ ((row & 7) << 4))) = sld[i];
    }
    __syncthreads();

    // 4) prefetch next step's gather (hidden under MFMA)
    if (s + 1 < MSTEPS) {
      int tok = utt[(s + 1) * NB + r0 + grow];
      const unsigned short* tb = tab + (size_t)tok * GD + c0 + gq * 8;
      pg0 = *(const u16x8*)(tb);
      pg1 = *(const u16x8*)(tb + ED);
      pg2 = *(const u16x8*)(tb + 2 * ED);
      #pragma unroll
      for (int a = 0; a < 2; a++)
        #pragma unroll
        for (int j = 0; j < 4; j++)
          ptoks[a * 4 + j] = utt[(s + 1) * NB + r0 + a * 16 + l4 * 4 + j];
    }

    // 5) gh = state @ Whh^T  (A from LDS, B from registers)
    f32x4 acc[2][3];
    #pragma unroll
    for (int a = 0; a < 2; a++)
      #pragma unroll
      for (int g = 0; g < 3; g++) acc[a][g] = (f32x4){0.f, 0.f, 0.f, 0.f};
    #pragma unroll
    for (int kk = 0; kk < 16; kk++) {
      s16x8 av[2];
      #pragma unroll
      for (int a = 0; a < 2; a++) {
        int row = a * 16 + l15;
        int ad = (row * 1024 + kk * 64 + l4 * 16) ^ ((row & 7) << 4);
        av[a] = *(const s16x8*)(sls + ad);
      }
      #pragma unroll
      for (int a = 0; a < 2; a++)
        #pragma unroll
        for (int g = 0; g < 3; g++)
          acc[a][g] = __builtin_amdgcn_mfma_f32_16x16x32_bf16(av[a], bfr[g][kk], acc[a][g], 0, 0, 0);
    }

    // 6) epilogue: gates + blend (f32 master state in regs)
    #pragma unroll
    for (int a = 0; a < 2; a++) {
      #pragma unroll
      for (int j = 0; j < 4; j++) {
        int row = a * 16 + l4 * 4 + j;
        float hr = acc[a][0][j] + bh[0];
        float hz = acc[a][1][j] + bh[1];
        float hn = acc[a][2][j] + bh[2];
        float ir = bf2f(gil[row * GIST + 0 * 64 + wc]);
        float iz = bf2f(gil[row * GIST + 1 * 64 + wc]);
        float in_ = bf2f(gil[row * GIST + 2 * 64 + wc]);
        float r = sigm(ir + hr);
        float z = sigm(iz + hz);
        float nn = tanh_(in_ + r * hn);
        float old = ms[a][j];
        float nu = (1.0f - z) * nn + z * old;
        float res = ((am >> (a * 4 + j)) & 1u) ? nu : old;
        ms[a][j] = res;
        stl[row * STST + wc] = f2bf(res);
        if (tk[a * 4 + j] == termid) am &= ~(1u << (a * 4 + j));
      }
    }
    __syncthreads();

    // 7) cooperative coherent store of new state tile (4KB/WG)
    {
      union { u16x8 v; unsigned long long u[2]; } cv;
      cv.v = *(const u16x8*)(stl + grow * STST + gq * 8);
      unsigned long long* dst =
          (unsigned long long*)(wrb + (size_t)(r0 + grow) * ED + c0 + gq * 8);
      __hip_atomic_store(dst, cv.u[0], __ATOMIC_RELAXED, __HIP_MEMORY_SCOPE_AGENT);
      __hip_atomic_store(dst + 1, cv.u[1], __ATOMIC_RELAXED, __HIP_MEMORY_SCOPE_AGENT);
    }

    // 8) per-row-block barrier (8 WGs), timeout -> abort (no hang)
    asm volatile("s_waitcnt vmcnt(0)" ::: "memory");
    __syncthreads();
    if (tid == 0) {
      __hip_atomic_fetch_add(cnt_r, 1u, __ATOMIC_RELEASE, __HIP_MEMORY_SCOPE_AGENT);
      unsigned target = (unsigned)NCB * (unsigned)(s + 1);
      unsigned long long t0 = __builtin_amdgcn_s_memrealtime();
      int ab = 0, pc = 0;
      while (__hip_atomic_load(cnt_r, __ATOMIC_RELAXED, __HIP_MEMORY_SCOPE_AGENT) < target) {
        if (((++pc) & 63) == 0) {
          if (__hip_atomic_load(abort_g, __ATOMIC_RELAXED, __HIP_MEMORY_SCOPE_AGENT)) { ab = 1; break; }
          if (__builtin_amdgcn_s_memrealtime() - t0 > 20000000ULL) {
            __hip_atomic_store(abort_g, 1, __ATOMIC_RELAXED, __HIP_MEMORY_SCOPE_AGENT);
            ab = 1; break;
          }
        }
      }
      abl = ab;
    }
    __syncthreads();
    if (abl) break;
  }

  // final f32 state -> d_out
  #pragma unroll
  for (int a = 0; a < 2; a++)
    #pragma unroll
    for (int j = 0; j < 4; j++) {
      int n = r0 + a * 16 + l4 * 4 + j;
      out[(size_t)n * ED + c0 + wc] = ms[a][j];
    }
}

__global__ void fail_kernel(float* out) {
  if (threadIdx.x == 0 && blockIdx.x == 0) out[0] = -54321.0f;
}

extern "C" void kernel_launch(void* const* d_in, const int* in_sizes, int n_in,
                              void* d_out, int out_size, void* d_ws, size_t ws_size,
                              hipStream_t stream) {
  const int* utt = (const int*)d_in[0];
  const float* emb = (const float*)d_in[1];
  const float* Wih = (const float*)d_in[2];
  const float* Whh = (const float*)d_in[3];
  const float* bih = (const float*)d_in[4];
  const float* bhh = (const float*)d_in[5];
  const int* term = (const int*)d_in[6];
  float* out = (float*)d_out;
  char* ws = (char*)d_ws;

  const size_t tab_b = (size_t)VS * GD * 2;                 // 98,304,000
  const size_t st_b = (size_t)NB * ED * 2;                  // 1,048,576
  const size_t off_st0 = tab_b;
  const size_t off_st1 = off_st0 + st_b;
  const size_t off_cnt = off_st1 + st_b;
  const size_t need = off_cnt + 8192;

  if (ws_size < need) {  // sentinel: visible failure instead of OOB
    fail_kernel<<<1, 64, 0, stream>>>(out);
    return;
  }

  unsigned short* tab = (unsigned short*)(ws);
  unsigned short* st0 = (unsigned short*)(ws + off_st0);
  unsigned short* st1 = (unsigned short*)(ws + off_st1);
  unsigned* cnt = (unsigned*)(ws + off_cnt);
  int* abort_g = (int*)(ws + off_cnt + 6144);

  (void)hipMemsetAsync(st0, 0, st_b, stream);
  (void)hipMemsetAsync(cnt, 0, 8192, stream);

  table_kernel<<<dim3(250, 12), 256, 0, stream>>>(emb, Wih, bih, tab);
  gru_kernel<<<256, 256, 0, stream>>>(utt, Whh, bhh, tab, st0, st1,
                                      cnt, abort_g, term, out);
}